// Round 1
// baseline (931.611 us; speedup 1.0000x reference)
//
#include <hip/hip_runtime.h>
#include <cstdint>
#include <cstddef>

// ---------------------------------------------------------------------------
// GCN forward on MI355X:
//   c_src = rsqrt(max(out_deg,1)), c_dst = rsqrt(max(in_deg,1))
//   t0 = (x @ W0) * c_src ; h1 = relu(csr_agg(t0) * c_dst + b0)
//   t1 = (h1 @ W1) * c_src ; h2 = csr_agg(t1) * c_dst + b1      (output 0)
//   logits = relu(h2) @ Wc + bc                                  (output 1)
// CSR (grouped-by-dst) built on device every launch (graph-capture safe).
// ---------------------------------------------------------------------------

static __device__ __forceinline__ float4 ld4(const float* p) { return *(const float4*)p; }

__global__ void deg_kernel(const int* __restrict__ src, const int* __restrict__ dst,
                           int* __restrict__ deg_o, int* __restrict__ deg_i, int E) {
  int e = blockIdx.x * blockDim.x + threadIdx.x;
  if (e < E) {
    atomicAdd(&deg_o[src[e]], 1);
    atomicAdd(&deg_i[dst[e]], 1);
  }
}

__global__ void norm_kernel(const int* __restrict__ deg_o, const int* __restrict__ deg_i,
                            float* __restrict__ c_src, float* __restrict__ c_dst, int n) {
  int i = blockIdx.x * blockDim.x + threadIdx.x;
  if (i < n) {
    c_src[i] = rsqrtf(fmaxf((float)deg_o[i], 1.0f));
    c_dst[i] = rsqrtf(fmaxf((float)deg_i[i], 1.0f));
  }
}

// Single-block exclusive scan of in-degrees -> row_start (N up to ~1M fine).
__global__ __launch_bounds__(1024) void scan_kernel(const int* __restrict__ deg_i,
                                                    int* __restrict__ row_start, int n) {
  __shared__ int sums[1024];
  int t = threadIdx.x;
  int chunk = max(1, (n + 1023) >> 10);
  int s0 = t * chunk;
  int s1 = min(s0 + chunk, n);
  int sum = 0;
  for (int i = s0; i < s1; i++) sum += deg_i[i];
  sums[t] = sum;
  __syncthreads();
  for (int off = 1; off < 1024; off <<= 1) {
    int v = (t >= off) ? sums[t - off] : 0;
    __syncthreads();
    if (t >= off) sums[t] += v;
    __syncthreads();
  }
  int run = sums[t] - sum;  // exclusive prefix for this chunk
  for (int i = s0; i < s1; i++) { row_start[i] = run; run += deg_i[i]; }
  if (t == 1023) row_start[n] = run;
}

__global__ void fill_csr(const int* __restrict__ src, const int* __restrict__ dst,
                         const int* __restrict__ row_start, int* __restrict__ cursor,
                         int* __restrict__ csr_src, int E) {
  int e = blockIdx.x * blockDim.x + threadIdx.x;
  if (e < E) {
    int d = dst[e];
    int pos = atomicAdd(&cursor[d], 1);
    csr_src[row_start[d] + pos] = src[e];
  }
}

// Y[n,128] = (A[n,K] @ W[K,128]) * c[n]   (fp32 tiled: BM=64, BN=128, BK=32)
template <int K>
__global__ __launch_bounds__(256) void gemm_scale(const float* __restrict__ A,
                                                  const float* __restrict__ W,
                                                  const float* __restrict__ c,
                                                  float* __restrict__ Y, int n) {
  __shared__ float As[64][36];    // 64 rows x 32 k (pad to 36 for aligned float4 writes)
  __shared__ float Bs[32][128];   // 32 k x 128 cols
  int tid = threadIdx.x;
  int tx = tid & 15;              // 16 col-groups * 8 cols
  int ty = tid >> 4;              // 16 row-groups * 4 rows
  int row0 = blockIdx.x * 64;
  float acc[4][8];
#pragma unroll
  for (int i = 0; i < 4; i++)
#pragma unroll
    for (int j = 0; j < 8; j++) acc[i][j] = 0.0f;

  for (int kt = 0; kt < K; kt += 32) {
#pragma unroll
    for (int l = 0; l < 2; l++) {
      int idx = tid + l * 256;          // 512 float4s = 64x32 floats
      int m = idx >> 3, q = idx & 7;
      int gr = row0 + m;
      float4 v = make_float4(0.f, 0.f, 0.f, 0.f);
      if (gr < n) v = ld4(&A[(size_t)gr * K + kt + q * 4]);
      *(float4*)&As[m][q * 4] = v;
    }
#pragma unroll
    for (int l = 0; l < 4; l++) {
      int idx = tid + l * 256;          // 1024 float4s = 32x128 floats
      int kk = idx >> 5, q = idx & 31;
      *(float4*)&Bs[kk][q * 4] = ld4(&W[(size_t)(kt + kk) * 128 + q * 4]);
    }
    __syncthreads();
#pragma unroll
    for (int k = 0; k < 32; k++) {
      float a[4];
#pragma unroll
      for (int i = 0; i < 4; i++) a[i] = As[ty * 4 + i][k];
      float4 b0 = *(float4*)&Bs[k][tx * 8];
      float4 b1 = *(float4*)&Bs[k][tx * 8 + 4];
      float b[8] = {b0.x, b0.y, b0.z, b0.w, b1.x, b1.y, b1.z, b1.w};
#pragma unroll
      for (int i = 0; i < 4; i++)
#pragma unroll
        for (int j = 0; j < 8; j++) acc[i][j] = fmaf(a[i], b[j], acc[i][j]);
    }
    __syncthreads();
  }
#pragma unroll
  for (int i = 0; i < 4; i++) {
    int r = row0 + ty * 4 + i;
    if (r < n) {
      float s = c[r];
      float4 o0 = make_float4(acc[i][0] * s, acc[i][1] * s, acc[i][2] * s, acc[i][3] * s);
      float4 o1 = make_float4(acc[i][4] * s, acc[i][5] * s, acc[i][6] * s, acc[i][7] * s);
      *(float4*)&Y[(size_t)r * 128 + tx * 8] = o0;
      *(float4*)&Y[(size_t)r * 128 + tx * 8 + 4] = o1;
    }
  }
}

// One wave per dst node; lane holds 2 features (float2). out = act(sum*c_dst + bias)
template <bool RELU>
__global__ __launch_bounds__(256) void agg_kernel(const float* __restrict__ T,
                                                  const int* __restrict__ row_start,
                                                  const int* __restrict__ csr_src,
                                                  const float* __restrict__ c_dst,
                                                  const float* __restrict__ bias,
                                                  float* __restrict__ out, int n) {
  int node = (blockIdx.x * 256 + threadIdx.x) >> 6;
  int lane = threadIdx.x & 63;
  if (node >= n) return;
  int e0 = row_start[node], e1 = row_start[node + 1];
  float ax = 0.f, ay = 0.f;
  int s_next = (e0 < e1) ? csr_src[e0] : 0;
  for (int e = e0; e < e1; e++) {
    int s = s_next;
    if (e + 1 < e1) s_next = csr_src[e + 1];   // prefetch next src id
    float2 v = *(const float2*)&T[(size_t)s * 128 + lane * 2];
    ax += v.x;
    ay += v.y;
  }
  float cd = c_dst[node];
  float rx = fmaf(ax, cd, bias[lane * 2]);
  float ry = fmaf(ay, cd, bias[lane * 2 + 1]);
  if (RELU) { rx = fmaxf(rx, 0.f); ry = fmaxf(ry, 0.f); }
  float2 r2;
  r2.x = rx;
  r2.y = ry;
  *(float2*)&out[(size_t)node * 128 + lane * 2] = r2;
}

// logits[n,40] = relu(H[n,128]) @ Wc[128,40] + bc
__global__ __launch_bounds__(256) void logits_kernel(const float* __restrict__ H,
                                                     const float* __restrict__ Wc,
                                                     const float* __restrict__ bc,
                                                     float* __restrict__ out, int n) {
  __shared__ float Wl[128 * 40];
  for (int i = threadIdx.x; i < 128 * 40; i += 256) Wl[i] = Wc[i];
  __syncthreads();
  int rl = threadIdx.x >> 3;  // 32 rows per block
  int cg = threadIdx.x & 7;   // 8 col-groups * 5 cols
  int r = blockIdx.x * 32 + rl;
  if (r >= n) return;
  float acc[5] = {0.f, 0.f, 0.f, 0.f, 0.f};
  const float* hr = &H[(size_t)r * 128];
  for (int k = 0; k < 128; k++) {
    float v = fmaxf(hr[k], 0.f);
#pragma unroll
    for (int j = 0; j < 5; j++) acc[j] = fmaf(v, Wl[k * 40 + cg * 5 + j], acc[j]);
  }
#pragma unroll
  for (int j = 0; j < 5; j++) out[(size_t)r * 40 + cg * 5 + j] = acc[j] + bc[cg * 5 + j];
}

extern "C" void kernel_launch(void* const* d_in, const int* in_sizes, int n_in,
                              void* d_out, int out_size, void* d_ws, size_t ws_size,
                              hipStream_t stream) {
  const float* x = (const float*)d_in[0];
  const int* src = (const int*)d_in[1];
  const int* dst = (const int*)d_in[2];
  const float* W0 = (const float*)d_in[3];
  const float* b0 = (const float*)d_in[4];
  const float* W1 = (const float*)d_in[5];
  const float* b1 = (const float*)d_in[6];
  const float* Wc = (const float*)d_in[7];
  const float* bc = (const float*)d_in[8];
  const int n = in_sizes[0] / 256;
  const int E = in_sizes[1];

  // --- workspace bump allocator (256B aligned) ---
  char* wsp = (char*)d_ws;
  auto alloc = [&](size_t bytes) -> char* {
    char* p = wsp;
    wsp += (bytes + 255) & ~(size_t)255;
    return p;
  };
  float* buf_t = (float*)alloc((size_t)n * 128 * sizeof(float));  // transformed feats
  float* c_src = (float*)alloc((size_t)n * sizeof(float));
  float* c_dst = (float*)alloc((size_t)n * sizeof(float));
  int* zero3 = (int*)alloc((size_t)3 * n * sizeof(int));  // deg_o | deg_i | cursor
  int* deg_o = zero3;
  int* deg_i = zero3 + n;
  int* cursor = zero3 + 2 * (size_t)n;
  int* row_start = (int*)alloc((size_t)(n + 1) * sizeof(int));
  int* csr = (int*)alloc((size_t)E * sizeof(int));

  float* h_out = (float*)d_out;               // n x 128 (h1 staged here, then h2)
  float* logits = h_out + (size_t)n * 128;    // n x 40

  hipMemsetAsync(zero3, 0, (size_t)3 * n * sizeof(int), stream);
  deg_kernel<<<(E + 255) / 256, 256, 0, stream>>>(src, dst, deg_o, deg_i, E);
  norm_kernel<<<(n + 255) / 256, 256, 0, stream>>>(deg_o, deg_i, c_src, c_dst, n);
  scan_kernel<<<1, 1024, 0, stream>>>(deg_i, row_start, n);
  fill_csr<<<(E + 255) / 256, 256, 0, stream>>>(src, dst, row_start, cursor, csr, E);

  // layer 0: t0 = (x @ W0) * c_src ; h1 = relu(agg * c_dst + b0)  -> h_out
  gemm_scale<256><<<(n + 63) / 64, 256, 0, stream>>>(x, W0, c_src, buf_t, n);
  agg_kernel<true><<<(n + 3) / 4, 256, 0, stream>>>(buf_t, row_start, csr, c_dst, b0, h_out, n);

  // layer 1: t1 = (h1 @ W1) * c_src ; h2 = agg * c_dst + b1       -> h_out
  gemm_scale<128><<<(n + 63) / 64, 256, 0, stream>>>(h_out, W1, c_src, buf_t, n);
  agg_kernel<false><<<(n + 3) / 4, 256, 0, stream>>>(buf_t, row_start, csr, c_dst, b1, h_out, n);

  // logits = relu(h2) @ Wc + bc
  logits_kernel<<<(n + 31) / 32, 256, 0, stream>>>(h_out, Wc, bc, logits, n);
}

// Round 2
// 807.782 us; speedup vs baseline: 1.1533x; 1.1533x over previous
//
#include <hip/hip_runtime.h>
#include <cstdint>
#include <cstddef>

// ---------------------------------------------------------------------------
// GCN forward on MI355X:
//   c_src = rsqrt(max(out_deg,1)), c_dst = rsqrt(max(in_deg,1))
//   t0 = (x @ W0) * c_src ; h1 = relu(csr_agg(t0) * c_dst + b0)
//   t1 = (h1 @ W1) * c_src ; h2 = csr_agg(t1) * c_dst + b1      (output 0)
//   logits = relu(h2) @ Wc + bc                                  (output 1)
// CSR (grouped-by-dst) built on device every launch (graph-capture safe).
// R2: replaced 162us single-block scan with 3-kernel multi-block scan.
// ---------------------------------------------------------------------------

static __device__ __forceinline__ float4 ld4(const float* p) { return *(const float4*)p; }

__global__ void deg_kernel(const int* __restrict__ src, const int* __restrict__ dst,
                           int* __restrict__ deg_o, int* __restrict__ deg_i, int E) {
  int e = blockIdx.x * blockDim.x + threadIdx.x;
  if (e < E) {
    atomicAdd(&deg_o[src[e]], 1);
    atomicAdd(&deg_i[dst[e]], 1);
  }
}

__global__ void norm_kernel(const int* __restrict__ deg_o, const int* __restrict__ deg_i,
                            float* __restrict__ c_src, float* __restrict__ c_dst, int n) {
  int i = blockIdx.x * blockDim.x + threadIdx.x;
  if (i < n) {
    c_src[i] = rsqrtf(fmaxf((float)deg_o[i], 1.0f));
    c_dst[i] = rsqrtf(fmaxf((float)deg_i[i], 1.0f));
  }
}

// --- multi-block exclusive scan of deg_i -> row_start (3 kernels) ---------
__global__ __launch_bounds__(256) void scan_partial(const int* __restrict__ deg,
                                                    int* __restrict__ partials, int n) {
  __shared__ int lds[256];
  int i = blockIdx.x * 256 + threadIdx.x;
  lds[threadIdx.x] = (i < n) ? deg[i] : 0;
  __syncthreads();
#pragma unroll
  for (int off = 128; off > 0; off >>= 1) {
    if (threadIdx.x < off) lds[threadIdx.x] += lds[threadIdx.x + off];
    __syncthreads();
  }
  if (threadIdx.x == 0) partials[blockIdx.x] = lds[0];
}

// single block scans up to 1024 block-partials (nb=391 for N=100K)
__global__ __launch_bounds__(1024) void scan_blocksums(int* __restrict__ partials, int nb) {
  __shared__ int lds[1024];
  int t = threadIdx.x;
  int v = (t < nb) ? partials[t] : 0;
  lds[t] = v;
  __syncthreads();
#pragma unroll
  for (int off = 1; off < 1024; off <<= 1) {
    int u = (t >= off) ? lds[t - off] : 0;
    __syncthreads();
    lds[t] += u;
    __syncthreads();
  }
  if (t < nb) partials[t] = lds[t] - v;  // exclusive
}

__global__ __launch_bounds__(256) void scan_final(const int* __restrict__ deg,
                                                  const int* __restrict__ partials,
                                                  int* __restrict__ row_start, int n) {
  __shared__ int lds[256];
  int i = blockIdx.x * 256 + threadIdx.x;
  int v = (i < n) ? deg[i] : 0;
  lds[threadIdx.x] = v;
  __syncthreads();
#pragma unroll
  for (int off = 1; off < 256; off <<= 1) {
    int u = (threadIdx.x >= off) ? lds[threadIdx.x - off] : 0;
    __syncthreads();
    lds[threadIdx.x] += u;
    __syncthreads();
  }
  int excl = lds[threadIdx.x] - v + partials[blockIdx.x];
  if (i < n) row_start[i] = excl;
  if (i == n - 1) row_start[n] = excl + v;  // total = E
}

__global__ void fill_csr(const int* __restrict__ src, const int* __restrict__ dst,
                         const int* __restrict__ row_start, int* __restrict__ cursor,
                         int* __restrict__ csr_src, int E) {
  int e = blockIdx.x * blockDim.x + threadIdx.x;
  if (e < E) {
    int d = dst[e];
    int pos = atomicAdd(&cursor[d], 1);
    csr_src[row_start[d] + pos] = src[e];
  }
}

// Y[n,128] = (A[n,K] @ W[K,128]) * c[n]   (fp32 tiled: BM=64, BN=128, BK=32)
template <int K>
__global__ __launch_bounds__(256) void gemm_scale(const float* __restrict__ A,
                                                  const float* __restrict__ W,
                                                  const float* __restrict__ c,
                                                  float* __restrict__ Y, int n) {
  __shared__ float As[64][36];    // 64 rows x 32 k (pad to 36 for aligned float4 writes)
  __shared__ float Bs[32][128];   // 32 k x 128 cols
  int tid = threadIdx.x;
  int tx = tid & 15;              // 16 col-groups * 8 cols
  int ty = tid >> 4;              // 16 row-groups * 4 rows
  int row0 = blockIdx.x * 64;
  float acc[4][8];
#pragma unroll
  for (int i = 0; i < 4; i++)
#pragma unroll
    for (int j = 0; j < 8; j++) acc[i][j] = 0.0f;

  for (int kt = 0; kt < K; kt += 32) {
#pragma unroll
    for (int l = 0; l < 2; l++) {
      int idx = tid + l * 256;          // 512 float4s = 64x32 floats
      int m = idx >> 3, q = idx & 7;
      int gr = row0 + m;
      float4 v = make_float4(0.f, 0.f, 0.f, 0.f);
      if (gr < n) v = ld4(&A[(size_t)gr * K + kt + q * 4]);
      *(float4*)&As[m][q * 4] = v;
    }
#pragma unroll
    for (int l = 0; l < 4; l++) {
      int idx = tid + l * 256;          // 1024 float4s = 32x128 floats
      int kk = idx >> 5, q = idx & 31;
      *(float4*)&Bs[kk][q * 4] = ld4(&W[(size_t)(kt + kk) * 128 + q * 4]);
    }
    __syncthreads();
#pragma unroll
    for (int k = 0; k < 32; k++) {
      float a[4];
#pragma unroll
      for (int i = 0; i < 4; i++) a[i] = As[ty * 4 + i][k];
      float4 b0 = *(float4*)&Bs[k][tx * 8];
      float4 b1 = *(float4*)&Bs[k][tx * 8 + 4];
      float b[8] = {b0.x, b0.y, b0.z, b0.w, b1.x, b1.y, b1.z, b1.w};
#pragma unroll
      for (int i = 0; i < 4; i++)
#pragma unroll
        for (int j = 0; j < 8; j++) acc[i][j] = fmaf(a[i], b[j], acc[i][j]);
    }
    __syncthreads();
  }
#pragma unroll
  for (int i = 0; i < 4; i++) {
    int r = row0 + ty * 4 + i;
    if (r < n) {
      float s = c[r];
      float4 o0 = make_float4(acc[i][0] * s, acc[i][1] * s, acc[i][2] * s, acc[i][3] * s);
      float4 o1 = make_float4(acc[i][4] * s, acc[i][5] * s, acc[i][6] * s, acc[i][7] * s);
      *(float4*)&Y[(size_t)r * 128 + tx * 8] = o0;
      *(float4*)&Y[(size_t)r * 128 + tx * 8 + 4] = o1;
    }
  }
}

// One wave per dst node; lane holds 2 features (float2). out = act(sum*c_dst + bias)
template <bool RELU>
__global__ __launch_bounds__(256) void agg_kernel(const float* __restrict__ T,
                                                  const int* __restrict__ row_start,
                                                  const int* __restrict__ csr_src,
                                                  const float* __restrict__ c_dst,
                                                  const float* __restrict__ bias,
                                                  float* __restrict__ out, int n) {
  int node = (blockIdx.x * 256 + threadIdx.x) >> 6;
  int lane = threadIdx.x & 63;
  if (node >= n) return;
  int e0 = row_start[node], e1 = row_start[node + 1];
  float ax = 0.f, ay = 0.f;
  int s_next = (e0 < e1) ? csr_src[e0] : 0;
  for (int e = e0; e < e1; e++) {
    int s = s_next;
    if (e + 1 < e1) s_next = csr_src[e + 1];   // prefetch next src id
    float2 v = *(const float2*)&T[(size_t)s * 128 + lane * 2];
    ax += v.x;
    ay += v.y;
  }
  float cd = c_dst[node];
  float rx = fmaf(ax, cd, bias[lane * 2]);
  float ry = fmaf(ay, cd, bias[lane * 2 + 1]);
  if (RELU) { rx = fmaxf(rx, 0.f); ry = fmaxf(ry, 0.f); }
  float2 r2;
  r2.x = rx;
  r2.y = ry;
  *(float2*)&out[(size_t)node * 128 + lane * 2] = r2;
}

// logits[n,40] = relu(H[n,128]) @ Wc[128,40] + bc
__global__ __launch_bounds__(256) void logits_kernel(const float* __restrict__ H,
                                                     const float* __restrict__ Wc,
                                                     const float* __restrict__ bc,
                                                     float* __restrict__ out, int n) {
  __shared__ float Wl[128 * 40];
  for (int i = threadIdx.x; i < 128 * 40; i += 256) Wl[i] = Wc[i];
  __syncthreads();
  int rl = threadIdx.x >> 3;  // 32 rows per block
  int cg = threadIdx.x & 7;   // 8 col-groups * 5 cols
  int r = blockIdx.x * 32 + rl;
  if (r >= n) return;
  float acc[5] = {0.f, 0.f, 0.f, 0.f, 0.f};
  const float* hr = &H[(size_t)r * 128];
  for (int k = 0; k < 128; k++) {
    float v = fmaxf(hr[k], 0.f);
#pragma unroll
    for (int j = 0; j < 5; j++) acc[j] = fmaf(v, Wl[k * 40 + cg * 5 + j], acc[j]);
  }
#pragma unroll
  for (int j = 0; j < 5; j++) out[(size_t)r * 40 + cg * 5 + j] = acc[j] + bc[cg * 5 + j];
}

extern "C" void kernel_launch(void* const* d_in, const int* in_sizes, int n_in,
                              void* d_out, int out_size, void* d_ws, size_t ws_size,
                              hipStream_t stream) {
  const float* x = (const float*)d_in[0];
  const int* src = (const int*)d_in[1];
  const int* dst = (const int*)d_in[2];
  const float* W0 = (const float*)d_in[3];
  const float* b0 = (const float*)d_in[4];
  const float* W1 = (const float*)d_in[5];
  const float* b1 = (const float*)d_in[6];
  const float* Wc = (const float*)d_in[7];
  const float* bc = (const float*)d_in[8];
  const int n = in_sizes[0] / 256;
  const int E = in_sizes[1];

  // --- workspace bump allocator (256B aligned) ---
  char* wsp = (char*)d_ws;
  auto alloc = [&](size_t bytes) -> char* {
    char* p = wsp;
    wsp += (bytes + 255) & ~(size_t)255;
    return p;
  };
  float* buf_t = (float*)alloc((size_t)n * 128 * sizeof(float));  // transformed feats
  float* c_src = (float*)alloc((size_t)n * sizeof(float));
  float* c_dst = (float*)alloc((size_t)n * sizeof(float));
  int* zero3 = (int*)alloc((size_t)3 * n * sizeof(int));  // deg_o | deg_i | cursor
  int* deg_o = zero3;
  int* deg_i = zero3 + n;
  int* cursor = zero3 + 2 * (size_t)n;
  int* row_start = (int*)alloc((size_t)(n + 1) * sizeof(int));
  int* partials = (int*)alloc((size_t)1024 * sizeof(int));
  int* csr = (int*)alloc((size_t)E * sizeof(int));

  float* h_out = (float*)d_out;               // n x 128 (h1 staged here, then h2)
  float* logits = h_out + (size_t)n * 128;    // n x 40

  const int nb = (n + 255) / 256;  // scan blocks (391 for N=100K; must be <=1024)

  hipMemsetAsync(zero3, 0, (size_t)3 * n * sizeof(int), stream);
  deg_kernel<<<(E + 255) / 256, 256, 0, stream>>>(src, dst, deg_o, deg_i, E);
  norm_kernel<<<(n + 255) / 256, 256, 0, stream>>>(deg_o, deg_i, c_src, c_dst, n);
  scan_partial<<<nb, 256, 0, stream>>>(deg_i, partials, n);
  scan_blocksums<<<1, 1024, 0, stream>>>(partials, nb);
  scan_final<<<nb, 256, 0, stream>>>(deg_i, partials, row_start, n);
  fill_csr<<<(E + 255) / 256, 256, 0, stream>>>(src, dst, row_start, cursor, csr, E);

  // layer 0: t0 = (x @ W0) * c_src ; h1 = relu(agg * c_dst + b0)  -> h_out
  gemm_scale<256><<<(n + 63) / 64, 256, 0, stream>>>(x, W0, c_src, buf_t, n);
  agg_kernel<true><<<(n + 3) / 4, 256, 0, stream>>>(buf_t, row_start, csr, c_dst, b0, h_out, n);

  // layer 1: t1 = (h1 @ W1) * c_src ; h2 = agg * c_dst + b1       -> h_out
  gemm_scale<128><<<(n + 63) / 64, 256, 0, stream>>>(h_out, W1, c_src, buf_t, n);
  agg_kernel<false><<<(n + 3) / 4, 256, 0, stream>>>(buf_t, row_start, csr, c_dst, b1, h_out, n);

  // logits = relu(h2) @ Wc + bc
  logits_kernel<<<(n + 31) / 32, 256, 0, stream>>>(h_out, Wc, bc, logits, n);
}

// Round 3
// 754.835 us; speedup vs baseline: 1.2342x; 1.0701x over previous
//
#include <hip/hip_runtime.h>
#include <cstdint>
#include <cstddef>

// ---------------------------------------------------------------------------
// GCN forward on MI355X.
// R3: replica-expanded CSR build (8 bins/node) to cut atomic contention 8x;
//     counting atomic returns slot -> fill_csr is atomic-free; c_dst derived
//     from row_start (no in-degree histogram at all).
// ---------------------------------------------------------------------------

#define R_REP 8  // replicas per node (power of 2)

static __device__ __forceinline__ float4 ld4(const float* p) { return *(const float4*)p; }

// cnt[dst*8 + (e&7)] slot-counting atomic (returns pos), dego replicas.
__global__ void count_kernel(const int* __restrict__ src, const int* __restrict__ dst,
                             int* __restrict__ cnt, int* __restrict__ dego,
                             uint8_t* __restrict__ pos, int n, int E) {
  int e = blockIdx.x * blockDim.x + threadIdx.x;
  if (e < E) {
    int r = e & (R_REP - 1);
    int p = atomicAdd(&cnt[(size_t)dst[e] * R_REP + r], 1);
    pos[e] = (uint8_t)p;
    atomicAdd(&dego[(size_t)r * n + src[e]], 1);
  }
}

// c_src from summed out-degree replicas.
__global__ void norm_kernel(const int* __restrict__ dego, float* __restrict__ c_src, int n) {
  int i = blockIdx.x * blockDim.x + threadIdx.x;
  if (i < n) {
    int s = 0;
#pragma unroll
    for (int r = 0; r < R_REP; r++) s += dego[(size_t)r * n + i];
    c_src[i] = rsqrtf(fmaxf((float)s, 1.0f));
  }
}

// --- multi-block exclusive scan over nbins = n*R_REP elements --------------
// 1024 elements per block (256 threads x 4).
__global__ __launch_bounds__(256) void scan_partial(const int* __restrict__ v,
                                                    int* __restrict__ partials, int nbins) {
  __shared__ int lds[256];
  int base = blockIdx.x * 1024 + threadIdx.x * 4;
  int s = 0;
#pragma unroll
  for (int j = 0; j < 4; j++) s += (base + j < nbins) ? v[base + j] : 0;
  lds[threadIdx.x] = s;
  __syncthreads();
#pragma unroll
  for (int off = 128; off > 0; off >>= 1) {
    if (threadIdx.x < off) lds[threadIdx.x] += lds[threadIdx.x + off];
    __syncthreads();
  }
  if (threadIdx.x == 0) partials[blockIdx.x] = lds[0];
}

// single block scans up to 1024 block-partials (782 for nbins=800K)
__global__ __launch_bounds__(1024) void scan_blocksums(int* __restrict__ partials, int nb) {
  __shared__ int lds[1024];
  int t = threadIdx.x;
  int v = (t < nb) ? partials[t] : 0;
  lds[t] = v;
  __syncthreads();
#pragma unroll
  for (int off = 1; off < 1024; off <<= 1) {
    int u = (t >= off) ? lds[t - off] : 0;
    __syncthreads();
    lds[t] += u;
    __syncthreads();
  }
  if (t < nb) partials[t] = lds[t] - v;  // exclusive
}

__global__ __launch_bounds__(256) void scan_final(const int* __restrict__ v,
                                                  const int* __restrict__ partials,
                                                  int* __restrict__ row_start, int nbins) {
  __shared__ int lds[256];
  int base = blockIdx.x * 1024 + threadIdx.x * 4;
  int e[4];
  int s = 0;
#pragma unroll
  for (int j = 0; j < 4; j++) {
    e[j] = (base + j < nbins) ? v[base + j] : 0;
    s += e[j];
  }
  lds[threadIdx.x] = s;
  __syncthreads();
#pragma unroll
  for (int off = 1; off < 256; off <<= 1) {
    int u = (threadIdx.x >= off) ? lds[threadIdx.x - off] : 0;
    __syncthreads();
    lds[threadIdx.x] += u;
    __syncthreads();
  }
  int run = lds[threadIdx.x] - s + partials[blockIdx.x];
#pragma unroll
  for (int j = 0; j < 4; j++) {
    if (base + j < nbins) row_start[base + j] = run;
    run += e[j];
    if (base + j == nbins - 1) row_start[nbins] = run;  // total = E
  }
}

// atomic-free scatter: csr[row_start[bin] + pos[e]] = src[e]
__global__ void fill_csr(const int* __restrict__ src, const int* __restrict__ dst,
                         const int* __restrict__ row_start, const uint8_t* __restrict__ pos,
                         int* __restrict__ csr_src, int E) {
  int e = blockIdx.x * blockDim.x + threadIdx.x;
  if (e < E) {
    int bin = dst[e] * R_REP + (e & (R_REP - 1));
    csr_src[row_start[bin] + (int)pos[e]] = src[e];
  }
}

// Y[n,128] = (A[n,K] @ W[K,128]) * c[n]   (fp32 tiled: BM=64, BN=128, BK=32)
template <int K>
__global__ __launch_bounds__(256) void gemm_scale(const float* __restrict__ A,
                                                  const float* __restrict__ W,
                                                  const float* __restrict__ c,
                                                  float* __restrict__ Y, int n) {
  __shared__ float As[64][36];
  __shared__ float Bs[32][128];
  int tid = threadIdx.x;
  int tx = tid & 15;
  int ty = tid >> 4;
  int row0 = blockIdx.x * 64;
  float acc[4][8];
#pragma unroll
  for (int i = 0; i < 4; i++)
#pragma unroll
    for (int j = 0; j < 8; j++) acc[i][j] = 0.0f;

  for (int kt = 0; kt < K; kt += 32) {
#pragma unroll
    for (int l = 0; l < 2; l++) {
      int idx = tid + l * 256;
      int m = idx >> 3, q = idx & 7;
      int gr = row0 + m;
      float4 v = make_float4(0.f, 0.f, 0.f, 0.f);
      if (gr < n) v = ld4(&A[(size_t)gr * K + kt + q * 4]);
      *(float4*)&As[m][q * 4] = v;
    }
#pragma unroll
    for (int l = 0; l < 4; l++) {
      int idx = tid + l * 256;
      int kk = idx >> 5, q = idx & 31;
      *(float4*)&Bs[kk][q * 4] = ld4(&W[(size_t)(kt + kk) * 128 + q * 4]);
    }
    __syncthreads();
#pragma unroll
    for (int k = 0; k < 32; k++) {
      float a[4];
#pragma unroll
      for (int i = 0; i < 4; i++) a[i] = As[ty * 4 + i][k];
      float4 b0 = *(float4*)&Bs[k][tx * 8];
      float4 b1 = *(float4*)&Bs[k][tx * 8 + 4];
      float b[8] = {b0.x, b0.y, b0.z, b0.w, b1.x, b1.y, b1.z, b1.w};
#pragma unroll
      for (int i = 0; i < 4; i++)
#pragma unroll
        for (int j = 0; j < 8; j++) acc[i][j] = fmaf(a[i], b[j], acc[i][j]);
    }
    __syncthreads();
  }
#pragma unroll
  for (int i = 0; i < 4; i++) {
    int r = row0 + ty * 4 + i;
    if (r < n) {
      float s = c[r];
      float4 o0 = make_float4(acc[i][0] * s, acc[i][1] * s, acc[i][2] * s, acc[i][3] * s);
      float4 o1 = make_float4(acc[i][4] * s, acc[i][5] * s, acc[i][6] * s, acc[i][7] * s);
      *(float4*)&Y[(size_t)r * 128 + tx * 8] = o0;
      *(float4*)&Y[(size_t)r * 128 + tx * 8 + 4] = o1;
    }
  }
}

// One wave per dst node; lane holds 2 features. c_dst derived from row span.
template <bool RELU>
__global__ __launch_bounds__(256) void agg_kernel(const float* __restrict__ T,
                                                  const int* __restrict__ row_start,
                                                  const int* __restrict__ csr_src,
                                                  const float* __restrict__ bias,
                                                  float* __restrict__ out, int n) {
  int node = (blockIdx.x * 256 + threadIdx.x) >> 6;
  int lane = threadIdx.x & 63;
  if (node >= n) return;
  int e0 = row_start[node * R_REP], e1 = row_start[node * R_REP + R_REP];
  float ax = 0.f, ay = 0.f;
  int s_next = (e0 < e1) ? csr_src[e0] : 0;
  for (int e = e0; e < e1; e++) {
    int s = s_next;
    if (e + 1 < e1) s_next = csr_src[e + 1];
    float2 v = *(const float2*)&T[(size_t)s * 128 + lane * 2];
    ax += v.x;
    ay += v.y;
  }
  float cd = rsqrtf(fmaxf((float)(e1 - e0), 1.0f));
  float rx = fmaf(ax, cd, bias[lane * 2]);
  float ry = fmaf(ay, cd, bias[lane * 2 + 1]);
  if (RELU) { rx = fmaxf(rx, 0.f); ry = fmaxf(ry, 0.f); }
  float2 r2;
  r2.x = rx;
  r2.y = ry;
  *(float2*)&out[(size_t)node * 128 + lane * 2] = r2;
}

// logits[n,40] = relu(H[n,128]) @ Wc[128,40] + bc
__global__ __launch_bounds__(256) void logits_kernel(const float* __restrict__ H,
                                                     const float* __restrict__ Wc,
                                                     const float* __restrict__ bc,
                                                     float* __restrict__ out, int n) {
  __shared__ float Wl[128 * 40];
  for (int i = threadIdx.x; i < 128 * 40; i += 256) Wl[i] = Wc[i];
  __syncthreads();
  int rl = threadIdx.x >> 3;
  int cg = threadIdx.x & 7;
  int r = blockIdx.x * 32 + rl;
  if (r >= n) return;
  float acc[5] = {0.f, 0.f, 0.f, 0.f, 0.f};
  const float* hr = &H[(size_t)r * 128];
  for (int k = 0; k < 128; k++) {
    float v = fmaxf(hr[k], 0.f);
#pragma unroll
    for (int j = 0; j < 5; j++) acc[j] = fmaf(v, Wl[k * 40 + cg * 5 + j], acc[j]);
  }
#pragma unroll
  for (int j = 0; j < 5; j++) out[(size_t)r * 40 + cg * 5 + j] = acc[j] + bc[cg * 5 + j];
}

extern "C" void kernel_launch(void* const* d_in, const int* in_sizes, int n_in,
                              void* d_out, int out_size, void* d_ws, size_t ws_size,
                              hipStream_t stream) {
  const float* x = (const float*)d_in[0];
  const int* src = (const int*)d_in[1];
  const int* dst = (const int*)d_in[2];
  const float* W0 = (const float*)d_in[3];
  const float* b0 = (const float*)d_in[4];
  const float* W1 = (const float*)d_in[5];
  const float* b1 = (const float*)d_in[6];
  const float* Wc = (const float*)d_in[7];
  const float* bc = (const float*)d_in[8];
  const int n = in_sizes[0] / 256;
  const int E = in_sizes[1];
  const int nbins = n * R_REP;

  // --- workspace bump allocator (256B aligned) ---
  char* wsp = (char*)d_ws;
  auto alloc = [&](size_t bytes) -> char* {
    char* p = wsp;
    wsp += (bytes + 255) & ~(size_t)255;
    return p;
  };
  float* buf_t = (float*)alloc((size_t)n * 128 * sizeof(float));      // 51.2 MB
  float* c_src = (float*)alloc((size_t)n * sizeof(float));
  int* zeroed = (int*)alloc((size_t)(nbins + R_REP * n) * sizeof(int));  // cnt | dego
  int* cnt = zeroed;
  int* dego = zeroed + nbins;
  int* row_start = (int*)alloc((size_t)(nbins + 1) * sizeof(int));
  int* partials = (int*)alloc((size_t)1024 * sizeof(int));
  uint8_t* pos = (uint8_t*)alloc((size_t)E);
  int* csr = (int*)alloc((size_t)E * sizeof(int));

  float* h_out = (float*)d_out;             // n x 128
  float* logits = h_out + (size_t)n * 128;  // n x 40

  const int nb = (nbins + 1023) / 1024;  // 782 for N=100K (<=1024 required)

  hipMemsetAsync(zeroed, 0, (size_t)(nbins + R_REP * n) * sizeof(int), stream);
  count_kernel<<<(E + 255) / 256, 256, 0, stream>>>(src, dst, cnt, dego, pos, n, E);
  norm_kernel<<<(n + 255) / 256, 256, 0, stream>>>(dego, c_src, n);
  scan_partial<<<nb, 256, 0, stream>>>(cnt, partials, nbins);
  scan_blocksums<<<1, 1024, 0, stream>>>(partials, nb);
  scan_final<<<nb, 256, 0, stream>>>(cnt, partials, row_start, nbins);
  fill_csr<<<(E + 255) / 256, 256, 0, stream>>>(src, dst, row_start, pos, csr, E);

  // layer 0: t0 = (x @ W0) * c_src ; h1 = relu(agg * c_dst + b0)  -> h_out
  gemm_scale<256><<<(n + 63) / 64, 256, 0, stream>>>(x, W0, c_src, buf_t, n);
  agg_kernel<true><<<(n + 3) / 4, 256, 0, stream>>>(buf_t, row_start, csr, b0, h_out, n);

  // layer 1: t1 = (h1 @ W1) * c_src ; h2 = agg * c_dst + b1       -> h_out
  gemm_scale<128><<<(n + 63) / 64, 256, 0, stream>>>(h_out, W1, c_src, buf_t, n);
  agg_kernel<false><<<(n + 3) / 4, 256, 0, stream>>>(buf_t, row_start, csr, b1, h_out, n);

  // logits = relu(h2) @ Wc + bc
  logits_kernel<<<(n + 31) / 32, 256, 0, stream>>>(h_out, Wc, bc, logits, n);
}

// Round 4
// 717.576 us; speedup vs baseline: 1.2983x; 1.0519x over previous
//
#include <hip/hip_runtime.h>
#include <cstdint>
#include <cstddef>

// ---------------------------------------------------------------------------
// GCN forward on MI355X.
// R4: (a) fuse CSR-count (atomic-pipe-bound, 0.5% VALU) with layer-0 GEMM
//     (VALU-bound) in one role-split dispatch, 4:1 interleave; c_src applied
//     per-edge in agg1 to break the dependency.  (b) bf16 transformed
//     features t0/t1/h1 -> halves L3 gather traffic in both agg passes.
// ---------------------------------------------------------------------------

#define R_REP 8

static __device__ __forceinline__ float4 ld4(const float* p) { return *(const float4*)p; }

static __device__ __forceinline__ float bf2f(unsigned int u) {
  union { unsigned int i; float f; } x; x.i = u << 16; return x.f;
}
static __device__ __forceinline__ unsigned int f2bf(float f) {
  union { float f; unsigned int i; } x; x.f = f;
  unsigned int r = x.i + 0x7fff + ((x.i >> 16) & 1);  // RTN-even
  return r >> 16;
}

// ---- fused: count role (4 of 5 blocks) + layer-0 gemm role (1 of 5) -------
// count: cnt[dst*8+(e&7)] returning atomic -> pos[e]; dego replicas.
// gemm:  t0b[n,128](bf16) = x[n,256] @ W0[256,128]  (fp32 accum, NO scale)
__global__ __launch_bounds__(256, 6) void fused_count_gemm(
    const int* __restrict__ src, const int* __restrict__ dst,
    int* __restrict__ cnt, int* __restrict__ dego, uint8_t* __restrict__ pos,
    const float* __restrict__ x, const float* __restrict__ W0,
    ushort* __restrict__ t0b, int n, int E, int ngemm) {
  __shared__ float As[64][36];
  __shared__ float Bs[32][128];
  int b = blockIdx.x;
  int g = b / 5, r5 = b - g * 5;
  if (r5 < 4) {  // ---- count role ----
    int e = (g * 4 + r5) * 256 + threadIdx.x;
    if (e < E) {
      int rep = e & (R_REP - 1);
      int p = atomicAdd(&cnt[(size_t)dst[e] * R_REP + rep], 1);
      pos[e] = (uint8_t)p;
      atomicAdd(&dego[(size_t)rep * n + src[e]], 1);
    }
    return;
  }
  // ---- gemm role: tile g ----
  if (g >= ngemm) return;
  int tid = threadIdx.x;
  int tx = tid & 15;
  int ty = tid >> 4;
  int row0 = g * 64;
  float acc[4][8];
#pragma unroll
  for (int i = 0; i < 4; i++)
#pragma unroll
    for (int j = 0; j < 8; j++) acc[i][j] = 0.0f;

  for (int kt = 0; kt < 256; kt += 32) {
#pragma unroll
    for (int l = 0; l < 2; l++) {
      int idx = tid + l * 256;
      int m = idx >> 3, q = idx & 7;
      int gr = row0 + m;
      float4 v = make_float4(0.f, 0.f, 0.f, 0.f);
      if (gr < n) v = ld4(&x[(size_t)gr * 256 + kt + q * 4]);
      *(float4*)&As[m][q * 4] = v;
    }
#pragma unroll
    for (int l = 0; l < 4; l++) {
      int idx = tid + l * 256;
      int kk = idx >> 5, q = idx & 31;
      *(float4*)&Bs[kk][q * 4] = ld4(&W0[(size_t)(kt + kk) * 128 + q * 4]);
    }
    __syncthreads();
#pragma unroll
    for (int k = 0; k < 32; k++) {
      float a[4];
#pragma unroll
      for (int i = 0; i < 4; i++) a[i] = As[ty * 4 + i][k];
      float4 b0 = *(float4*)&Bs[k][tx * 8];
      float4 b1 = *(float4*)&Bs[k][tx * 8 + 4];
      float bb[8] = {b0.x, b0.y, b0.z, b0.w, b1.x, b1.y, b1.z, b1.w};
#pragma unroll
      for (int i = 0; i < 4; i++)
#pragma unroll
        for (int j = 0; j < 8; j++) acc[i][j] = fmaf(a[i], bb[j], acc[i][j]);
    }
    __syncthreads();
  }
#pragma unroll
  for (int i = 0; i < 4; i++) {
    int r = row0 + ty * 4 + i;
    if (r < n) {
      uint4 o;
      o.x = f2bf(acc[i][0]) | (f2bf(acc[i][1]) << 16);
      o.y = f2bf(acc[i][2]) | (f2bf(acc[i][3]) << 16);
      o.z = f2bf(acc[i][4]) | (f2bf(acc[i][5]) << 16);
      o.w = f2bf(acc[i][6]) | (f2bf(acc[i][7]) << 16);
      *(uint4*)&t0b[(size_t)r * 128 + tx * 8] = o;
    }
  }
}

// c_src from summed out-degree replicas.
__global__ void norm_kernel(const int* __restrict__ dego, float* __restrict__ c_src, int n) {
  int i = blockIdx.x * blockDim.x + threadIdx.x;
  if (i < n) {
    int s = 0;
#pragma unroll
    for (int r = 0; r < R_REP; r++) s += dego[(size_t)r * n + i];
    c_src[i] = rsqrtf(fmaxf((float)s, 1.0f));
  }
}

// --- multi-block exclusive scan over nbins = n*R_REP (1024 elems/block) ----
__global__ __launch_bounds__(256) void scan_partial(const int* __restrict__ v,
                                                    int* __restrict__ partials, int nbins) {
  __shared__ int lds[256];
  int base = blockIdx.x * 1024 + threadIdx.x * 4;
  int s = 0;
#pragma unroll
  for (int j = 0; j < 4; j++) s += (base + j < nbins) ? v[base + j] : 0;
  lds[threadIdx.x] = s;
  __syncthreads();
#pragma unroll
  for (int off = 128; off > 0; off >>= 1) {
    if (threadIdx.x < off) lds[threadIdx.x] += lds[threadIdx.x + off];
    __syncthreads();
  }
  if (threadIdx.x == 0) partials[blockIdx.x] = lds[0];
}

__global__ __launch_bounds__(1024) void scan_blocksums(int* __restrict__ partials, int nb) {
  __shared__ int lds[1024];
  int t = threadIdx.x;
  int v = (t < nb) ? partials[t] : 0;
  lds[t] = v;
  __syncthreads();
#pragma unroll
  for (int off = 1; off < 1024; off <<= 1) {
    int u = (t >= off) ? lds[t - off] : 0;
    __syncthreads();
    lds[t] += u;
    __syncthreads();
  }
  if (t < nb) partials[t] = lds[t] - v;  // exclusive
}

__global__ __launch_bounds__(256) void scan_final(const int* __restrict__ v,
                                                  const int* __restrict__ partials,
                                                  int* __restrict__ row_start, int nbins) {
  __shared__ int lds[256];
  int base = blockIdx.x * 1024 + threadIdx.x * 4;
  int e[4];
  int s = 0;
#pragma unroll
  for (int j = 0; j < 4; j++) {
    e[j] = (base + j < nbins) ? v[base + j] : 0;
    s += e[j];
  }
  lds[threadIdx.x] = s;
  __syncthreads();
#pragma unroll
  for (int off = 1; off < 256; off <<= 1) {
    int u = (threadIdx.x >= off) ? lds[threadIdx.x - off] : 0;
    __syncthreads();
    lds[threadIdx.x] += u;
    __syncthreads();
  }
  int run = lds[threadIdx.x] - s + partials[blockIdx.x];
#pragma unroll
  for (int j = 0; j < 4; j++) {
    if (base + j < nbins) row_start[base + j] = run;
    run += e[j];
    if (base + j == nbins - 1) row_start[nbins] = run;
  }
}

// atomic-free scatter
__global__ void fill_csr(const int* __restrict__ src, const int* __restrict__ dst,
                         const int* __restrict__ row_start, const uint8_t* __restrict__ pos,
                         int* __restrict__ csr_src, int E) {
  int e = blockIdx.x * blockDim.x + threadIdx.x;
  if (e < E) {
    int bin = dst[e] * R_REP + (e & (R_REP - 1));
    csr_src[row_start[bin] + (int)pos[e]] = src[e];
  }
}

// t1b[n,128](bf16) = (h1b[n,128](bf16) @ W1[128,128]) * c_src[n]  (fp32 accum)
__global__ __launch_bounds__(256) void gemm128_bf16(const ushort* __restrict__ A,
                                                    const float* __restrict__ W,
                                                    const float* __restrict__ c,
                                                    ushort* __restrict__ Y, int n) {
  __shared__ float As[64][36];
  __shared__ float Bs[32][128];
  int tid = threadIdx.x;
  int tx = tid & 15;
  int ty = tid >> 4;
  int row0 = blockIdx.x * 64;
  float acc[4][8];
#pragma unroll
  for (int i = 0; i < 4; i++)
#pragma unroll
    for (int j = 0; j < 8; j++) acc[i][j] = 0.0f;

  for (int kt = 0; kt < 128; kt += 32) {
    {  // stage A: 64 rows x 32 bf16 -> float; 8 elems/thread
      int m = tid >> 2, q = tid & 3;
      int gr = row0 + m;
      uint4 w = make_uint4(0u, 0u, 0u, 0u);
      if (gr < n) w = *(const uint4*)&A[(size_t)gr * 128 + kt + q * 8];
      float4 f0 = make_float4(bf2f(w.x & 0xffff), bf2f(w.x >> 16),
                              bf2f(w.y & 0xffff), bf2f(w.y >> 16));
      float4 f1 = make_float4(bf2f(w.z & 0xffff), bf2f(w.z >> 16),
                              bf2f(w.w & 0xffff), bf2f(w.w >> 16));
      *(float4*)&As[m][q * 8] = f0;
      *(float4*)&As[m][q * 8 + 4] = f1;
    }
#pragma unroll
    for (int l = 0; l < 4; l++) {
      int idx = tid + l * 256;
      int kk = idx >> 5, q = idx & 31;
      *(float4*)&Bs[kk][q * 4] = ld4(&W[(size_t)(kt + kk) * 128 + q * 4]);
    }
    __syncthreads();
#pragma unroll
    for (int k = 0; k < 32; k++) {
      float a[4];
#pragma unroll
      for (int i = 0; i < 4; i++) a[i] = As[ty * 4 + i][k];
      float4 b0 = *(float4*)&Bs[k][tx * 8];
      float4 b1 = *(float4*)&Bs[k][tx * 8 + 4];
      float bb[8] = {b0.x, b0.y, b0.z, b0.w, b1.x, b1.y, b1.z, b1.w};
#pragma unroll
      for (int i = 0; i < 4; i++)
#pragma unroll
        for (int j = 0; j < 8; j++) acc[i][j] = fmaf(a[i], bb[j], acc[i][j]);
    }
    __syncthreads();
  }
#pragma unroll
  for (int i = 0; i < 4; i++) {
    int r = row0 + ty * 4 + i;
    if (r < n) {
      float s = c[r];
      uint4 o;
      o.x = f2bf(acc[i][0] * s) | (f2bf(acc[i][1] * s) << 16);
      o.y = f2bf(acc[i][2] * s) | (f2bf(acc[i][3] * s) << 16);
      o.z = f2bf(acc[i][4] * s) | (f2bf(acc[i][5] * s) << 16);
      o.w = f2bf(acc[i][6] * s) | (f2bf(acc[i][7] * s) << 16);
      *(uint4*)&Y[(size_t)r * 128 + tx * 8] = o;
    }
  }
}

// One wave per dst node; lane holds 2 bf16 features (4B load per edge).
// SCALE: multiply each gathered row by c_src[s].  OUT_BF16: write bf16 pair.
template <bool RELU, bool SCALE, bool OUT_BF16>
__global__ __launch_bounds__(256) void agg_kernel(const ushort* __restrict__ T,
                                                  const int* __restrict__ row_start,
                                                  const int* __restrict__ csr_src,
                                                  const float* __restrict__ c_src,
                                                  const float* __restrict__ bias,
                                                  void* __restrict__ out, int n) {
  int node = (blockIdx.x * 256 + threadIdx.x) >> 6;
  int lane = threadIdx.x & 63;
  if (node >= n) return;
  int e0 = row_start[node * R_REP], e1 = row_start[node * R_REP + R_REP];
  float ax = 0.f, ay = 0.f;
  int e = e0;
  for (; e + 1 < e1; e += 2) {  // 2-wide: two gathers in flight
    int s0 = csr_src[e], s1 = csr_src[e + 1];
    unsigned int w0 = *(const unsigned int*)&T[(size_t)s0 * 128 + lane * 2];
    unsigned int w1 = *(const unsigned int*)&T[(size_t)s1 * 128 + lane * 2];
    float fx0 = bf2f(w0 & 0xffff), fy0 = bf2f(w0 >> 16);
    float fx1 = bf2f(w1 & 0xffff), fy1 = bf2f(w1 >> 16);
    if (SCALE) {
      float cs0 = c_src[s0], cs1 = c_src[s1];
      fx0 *= cs0; fy0 *= cs0; fx1 *= cs1; fy1 *= cs1;
    }
    ax += fx0 + fx1;
    ay += fy0 + fy1;
  }
  if (e < e1) {
    int s0 = csr_src[e];
    unsigned int w0 = *(const unsigned int*)&T[(size_t)s0 * 128 + lane * 2];
    float fx0 = bf2f(w0 & 0xffff), fy0 = bf2f(w0 >> 16);
    if (SCALE) { float cs0 = c_src[s0]; fx0 *= cs0; fy0 *= cs0; }
    ax += fx0;
    ay += fy0;
  }
  float cd = rsqrtf(fmaxf((float)(e1 - e0), 1.0f));
  float rx = fmaf(ax, cd, bias[lane * 2]);
  float ry = fmaf(ay, cd, bias[lane * 2 + 1]);
  if (RELU) { rx = fmaxf(rx, 0.f); ry = fmaxf(ry, 0.f); }
  if (OUT_BF16) {
    ((unsigned int*)out)[(size_t)node * 64 + lane] = f2bf(rx) | (f2bf(ry) << 16);
  } else {
    float2 r2; r2.x = rx; r2.y = ry;
    ((float2*)out)[(size_t)node * 64 + lane] = r2;
  }
}

// logits[n,40] = relu(H[n,128]) @ Wc[128,40] + bc
__global__ __launch_bounds__(256) void logits_kernel(const float* __restrict__ H,
                                                     const float* __restrict__ Wc,
                                                     const float* __restrict__ bc,
                                                     float* __restrict__ out, int n) {
  __shared__ float Wl[128 * 40];
  for (int i = threadIdx.x; i < 128 * 40; i += 256) Wl[i] = Wc[i];
  __syncthreads();
  int rl = threadIdx.x >> 3;
  int cg = threadIdx.x & 7;
  int r = blockIdx.x * 32 + rl;
  if (r >= n) return;
  float acc[5] = {0.f, 0.f, 0.f, 0.f, 0.f};
  const float* hr = &H[(size_t)r * 128];
  for (int k = 0; k < 128; k++) {
    float v = fmaxf(hr[k], 0.f);
#pragma unroll
    for (int j = 0; j < 5; j++) acc[j] = fmaf(v, Wl[k * 40 + cg * 5 + j], acc[j]);
  }
#pragma unroll
  for (int j = 0; j < 5; j++) out[(size_t)r * 40 + cg * 5 + j] = acc[j] + bc[cg * 5 + j];
}

extern "C" void kernel_launch(void* const* d_in, const int* in_sizes, int n_in,
                              void* d_out, int out_size, void* d_ws, size_t ws_size,
                              hipStream_t stream) {
  const float* x = (const float*)d_in[0];
  const int* src = (const int*)d_in[1];
  const int* dst = (const int*)d_in[2];
  const float* W0 = (const float*)d_in[3];
  const float* b0 = (const float*)d_in[4];
  const float* W1 = (const float*)d_in[5];
  const float* b1 = (const float*)d_in[6];
  const float* Wc = (const float*)d_in[7];
  const float* bc = (const float*)d_in[8];
  const int n = in_sizes[0] / 256;
  const int E = in_sizes[1];
  const int nbins = n * R_REP;

  char* wsp = (char*)d_ws;
  auto alloc = [&](size_t bytes) -> char* {
    char* p = wsp;
    wsp += (bytes + 255) & ~(size_t)255;
    return p;
  };
  ushort* t0b = (ushort*)alloc((size_t)n * 128 * sizeof(ushort));  // t0 / reused as t1
  ushort* h1b = (ushort*)alloc((size_t)n * 128 * sizeof(ushort));
  float* c_src = (float*)alloc((size_t)n * sizeof(float));
  int* zeroed = (int*)alloc((size_t)(nbins + R_REP * n) * sizeof(int));  // cnt | dego
  int* cnt = zeroed;
  int* dego = zeroed + nbins;
  int* row_start = (int*)alloc((size_t)(nbins + 1) * sizeof(int));
  int* partials = (int*)alloc((size_t)1024 * sizeof(int));
  uint8_t* pos = (uint8_t*)alloc((size_t)E);
  int* csr = (int*)alloc((size_t)E * sizeof(int));

  float* h_out = (float*)d_out;             // n x 128 (h2)
  float* logits = h_out + (size_t)n * 128;  // n x 40

  const int ngemm = (n + 63) / 64;                   // 1563
  const int nchunks = (E + 255) / 256;               // 6250
  const int ngrp = max(ngemm, (nchunks + 3) / 4);    // 1563
  const int nb = (nbins + 1023) / 1024;              // 782 (<=1024)

  hipMemsetAsync(zeroed, 0, (size_t)(nbins + R_REP * n) * sizeof(int), stream);
  // count (atomic-bound) || layer-0 gemm (VALU-bound), 4:1 interleave
  fused_count_gemm<<<ngrp * 5, 256, 0, stream>>>(src, dst, cnt, dego, pos, x, W0, t0b,
                                                 n, E, ngemm);
  norm_kernel<<<(n + 255) / 256, 256, 0, stream>>>(dego, c_src, n);
  scan_partial<<<nb, 256, 0, stream>>>(cnt, partials, nbins);
  scan_blocksums<<<1, 1024, 0, stream>>>(partials, nb);
  scan_final<<<nb, 256, 0, stream>>>(cnt, partials, row_start, nbins);
  fill_csr<<<(E + 255) / 256, 256, 0, stream>>>(src, dst, row_start, pos, csr, E);

  // h1b(bf16) = relu(agg(t0b * c_src[s]) * c_dst + b0)
  agg_kernel<true, true, true><<<(n + 3) / 4, 256, 0, stream>>>(
      t0b, row_start, csr, c_src, b0, (void*)h1b, n);
  // t1b(bf16) = (h1b @ W1) * c_src   (reuse t0b buffer)
  gemm128_bf16<<<(n + 63) / 64, 256, 0, stream>>>(h1b, W1, c_src, t0b, n);
  // h2(fp32, d_out) = agg(t1b) * c_dst + b1
  agg_kernel<false, false, false><<<(n + 3) / 4, 256, 0, stream>>>(
      t0b, row_start, csr, c_src, b1, (void*)h_out, n);
  // logits = relu(h2) @ Wc + bc
  logits_kernel<<<(n + 31) / 32, 256, 0, stream>>>(h_out, Wc, bc, logits, n);
}